// Round 20
// baseline (29.869 us; speedup 1.0000x reference)
//
#include <hip/hip_runtime.h>
#include <hip/hip_fp16.h>
#include <math.h>

#define D_DET 512
#define N_ANG 180
#define S_IMG 512
#define NPIX  (S_IMG * S_IMG)
#define T_MAX 63                 // ramp tap truncation
#define AG    72                 // global-pipe angles: 0..71
#define AL    108                // LDS-pipe angles: 72..179
#define WIN   32                 // LDS window cells (16x16 tile span <= 24)
#define CD    0.99984769515639124f   // cos(1 deg)
#define SD    0.01745240643728351f   // sin(1 deg)

typedef _Float16 half2v __attribute__((ext_vector_type(2)));

__device__ __constant__ float kPI = 3.14159265358979323846f;

__device__ __forceinline__ half2v pack_w1(float w) {
    return __builtin_bit_cast(half2v, __builtin_amdgcn_cvt_pkrtz(1.0f, w));
}

// ---------------------------------------------------------------------------
// Stage 1: ramp filter (R16 verbatim): truncated symmetric convolution,
// (f, DELTA) fp16 packing. word (a*512+d)*2+bc = fp16x2 (xf[d], xf[d+1]-xf[d]).
// Grid: 90 blocks = (bc, 4 angles) x 512 threads; float4 input loads.
// ---------------------------------------------------------------------------
__global__ __launch_bounds__(512) void ramp_filter_kernel(
    const float* __restrict__ x, unsigned* __restrict__ xfh) {
    __shared__ float rp[4][640];
    __shared__ float xf[4][D_DET + 1];

    const int blk = blockIdx.x;
    const int bc  = blk / 45;            // 0..1
    const int a0  = (blk % 45) * 4;
    const int d   = threadIdx.x;

    float4 q = *(const float4*)(x + (bc * D_DET + d) * N_ANG + a0);
    rp[0][64 + d] = q.x;
    rp[1][64 + d] = q.y;
    rp[2][64 + d] = q.z;
    rp[3][64 + d] = q.w;
    if (d < 64) {
        #pragma unroll
        for (int r = 0; r < 4; ++r) { rp[r][d] = 0.0f; rp[r][576 + d] = 0.0f; }
    }
    if (d < 4) xf[d][D_DET] = 0.0f;
    __syncthreads();

    constexpr float PI_ = 3.14159265358979323846f;
    #pragma unroll
    for (int r = 0; r < 4; ++r) {
        const float* rm = &rp[r][64 + d];
        float acc = 0.5f * rm[0];
        #pragma unroll
        for (int k = 0; k < (T_MAX + 1) / 2; ++k) {
            const int   t = 2 * k + 1;
            const float h = -2.0f / (PI_ * PI_ * (float)(t * t));
            acc = fmaf(rm[-t] + rm[t], h, acc);
        }
        xf[r][d] = acc;
    }
    __syncthreads();

    #pragma unroll
    for (int r = 0; r < 4; ++r) {
        const float f0 = xf[r][d];
        const float dl = xf[r][d + 1] - f0;
        const unsigned lo = __half_as_ushort(__float2half_rn(f0));
        const unsigned hi = __half_as_ushort(__float2half_rn(dl));
        xfh[((a0 + r) * D_DET + d) * 2 + bc] = (hi << 16) | lo;
    }
}

// ---------------------------------------------------------------------------
// Stage 2: backprojection, dual-pipe + ZERO per-iteration trig reads.
// pc recurrence: p' = CD*p - SD*q, q' = CD*q + SD*p (4 fma), re-seeded by
// sincosf every 36 angles (drift <= 2e-3 cells). Block = 512 thr over a
// 16x16 tile: half 0 -> angles 0..71 via GLOBAL gathers (vL1D pipe, no LDS
// ops at all); half 1 -> angles 72..179 via staged 32-cell windows (LDS
// pipe), per-angle bias batch-read as float4 every 4 iters.
// Per-CU ledger: vL1D 1152x16cyc=7.7us | LDS 1728x7+5.2k=8.0us | VALU 7.5us.
// ---------------------------------------------------------------------------
__global__ __launch_bounds__(512) void backproj_kernel(
    const uint2* __restrict__ xfh, float* __restrict__ out) {
    __shared__ float  dminF[AL];         // bias = 255.5 - dmin  (16B aligned)
    __shared__ int    dminI[AL];         // dmin (staging)
    __shared__ uint2  win[AL * WIN];     // 27.6 KB window buffer
    __shared__ float2 red[256];

    const int tid = threadIdx.x;
    const int bi  = blockIdx.x >> 5;     // 32 i-tiles of 16
    const int bj  = blockIdx.x & 31;     // 32 j-tiles of 16
    const int i0  = bi << 4;
    const int j0  = bj << 4;

    // Prologue: per-angle window start for LDS-half angles.
    if (tid < AL) {
        float th = (float)(AG + tid) * (kPI / 180.0f);
        float s, c;
        sincosf(th, &s, &c);
        float c5 = c * 255.5f, s5 = s * 255.5f;
        float x0 = (float)j0 * (2.0f / 511.0f) - 1.0f;
        float x1 = (float)(j0 + 15) * (2.0f / 511.0f) - 1.0f;
        float y0 = (float)i0 * (2.0f / 511.0f) - 1.0f;
        float y1 = (float)(i0 + 15) * (2.0f / 511.0f) - 1.0f;
        float pmin = 255.5f + fminf(c5 * x0, c5 * x1)
                            + fminf(-s5 * y0, -s5 * y1);
        int dmin = (int)floorf(pmin) - 1;
        dmin = dmin < 0 ? 0 : (dmin > (D_DET - WIN) ? (D_DET - WIN) : dmin);
        dmin &= ~1;                      // 16B-aligned staging source
        dminI[tid] = dmin;
        dminF[tid] = 255.5f - (float)dmin;
    }
    __syncthreads();

    // Stage windows: AL angles x 16 uint4, coalesced from L2.
    {
        const uint4* __restrict__ src4 = (const uint4*)xfh;
        uint4* win4 = (uint4*)win;
        for (int f = tid; f < AL * (WIN / 2); f += 512) {
            int a    = f >> 4;           // local angle, 16 uint4 per angle
            int e    = f & 15;
            int dmin = dminI[a];
            win4[f]  = src4[((((AG + a) << 9) + dmin) >> 1) + e];
        }
    }
    __syncthreads();

    const int half = tid >> 8;
    const int sub  = (tid >> 6) & 3;
    const int lane = tid & 63;
    const int px   = tid & 255;
    const int i = i0 + ((sub >> 1) << 3) + (lane >> 3);
    const int j = j0 + ((sub & 1) << 3) + (lane & 7);

    const float xP = (float)j * (2.0f / 511.0f) - 1.0f;
    const float yP = (float)i * (2.0f / 511.0f) - 1.0f;
    const float m  = xP * xP + yP * yP;
    const bool inc = (m <= 1.0f);
    const float xS = inc ? xP : 0.0f;    // sanitize: out-circle -> pc=255.5
    const float yS = inc ? yP : 0.0f;

    float a0 = 0.0f, a1 = 0.0f;
    if (__any(inc)) {
        if (half == 0) {
            // vL1D pipe: global gathers, trig fully in registers.
            #pragma unroll 1
            for (int c = 0; c < AG / 36; ++c) {
                const int abase = c * 36;
                float th = (float)abase * (kPI / 180.0f);
                float sn, cs;
                sincosf(th, &sn, &cs);
                float p = xS * (cs * 255.5f) - yS * (sn * 255.5f);
                float q = xS * (sn * 255.5f) + yS * (cs * 255.5f);
                #pragma unroll 6
                for (int k = 0; k < 36; ++k) {
                    float pc  = fmaxf(p + 255.5f, 0.0f);
                    int   fi  = (int)pc;
                    float w   = __builtin_amdgcn_fractf(pc);
                    half2v hw = pack_w1(w);
                    uint2  g  = xfh[((abase + k) << 9) + fi];
                    a0 = __builtin_amdgcn_fdot2(hw, __builtin_bit_cast(half2v, g.x), a0, false);
                    a1 = __builtin_amdgcn_fdot2(hw, __builtin_bit_cast(half2v, g.y), a1, false);
                    float pn = fmaf(CD, p, -SD * q);
                    q        = fmaf(CD, q,  SD * p);
                    p = pn;
                }
            }
        } else {
            // LDS pipe: window reads, bias batch-read as float4 / 4 iters.
            const float4* __restrict__ bias4 = (const float4*)dminF;
            #pragma unroll 1
            for (int c = 0; c < AL / 36; ++c) {
                const int abase = c * 36;          // local (0-based at AG)
                float th = (float)(AG + abase) * (kPI / 180.0f);
                float sn, cs;
                sincosf(th, &sn, &cs);
                float p = xS * (cs * 255.5f) - yS * (sn * 255.5f);
                float q = xS * (sn * 255.5f) + yS * (cs * 255.5f);
                #pragma unroll 3
                for (int gq = 0; gq < 9; ++gq) {
                    const float4 bs = bias4[c * 9 + gq];
                    #pragma unroll
                    for (int jj = 0; jj < 4; ++jj) {
                        const int al = abase + gq * 4 + jj;
                        const float bias = (jj == 0) ? bs.x : (jj == 1) ? bs.y
                                         : (jj == 2) ? bs.z : bs.w;
                        float pcW = fminf(fmaxf(p + bias, 0.0f), (float)(WIN - 1));
                        int   fi  = (int)pcW;
                        float w   = __builtin_amdgcn_fractf(pcW);
                        half2v hw = pack_w1(w);
                        uint2  g  = win[(al << 5) + fi];
                        a0 = __builtin_amdgcn_fdot2(hw, __builtin_bit_cast(half2v, g.x), a0, false);
                        a1 = __builtin_amdgcn_fdot2(hw, __builtin_bit_cast(half2v, g.y), a1, false);
                        float pn = fmaf(CD, p, -SD * q);
                        q        = fmaf(CD, q,  SD * p);
                        p = pn;
                    }
                }
            }
        }
    }

    if (half == 1) red[px] = make_float2(a0, a1);
    __syncthreads();
    if (half == 0) {
        const float2 r = red[px];
        const float msk = inc ? (kPI / (2.0f * (float)N_ANG)) : 0.0f;
        const int p = i * S_IMG + j;
        out[p]        = (a0 + r.x) * msk;
        out[NPIX + p] = (a1 + r.y) * msk;
    }
}

// ---------------------------------------------------------------------------
extern "C" void kernel_launch(void* const* d_in, const int* in_sizes, int n_in,
                              void* d_out, int out_size, void* d_ws, size_t ws_size,
                              hipStream_t stream) {
    const float* x   = (const float*)d_in[0];
    float*       out = (float*)d_out;
    unsigned*    xfh = (unsigned*)d_ws;  // 737,280 B

    ramp_filter_kernel<<<90, 512, 0, stream>>>(x, xfh);
    backproj_kernel<<<1024, 512, 0, stream>>>((const uint2*)xfh, out);
}

// Round 21
// 26.765 us; speedup vs baseline: 1.1160x; 1.1160x over previous
//
#include <hip/hip_runtime.h>
#include <hip/hip_fp16.h>
#include <math.h>

#define D_DET 512
#define N_ANG 180
#define S_IMG 512
#define NPIX  (S_IMG * S_IMG)
#define T_MAX 63                 // ramp tap truncation
#define AG    72                 // global-pipe angles: 0..71
#define AL    108                // LDS-pipe angles: 72..179
#define WIN   32                 // LDS window cells (16x16 tile span <= 26)

typedef _Float16 half2v __attribute__((ext_vector_type(2)));

struct TrigTab { float2 cs[N_ANG]; };  // (cos*255.5, sin*255.5), host-computed

__device__ __constant__ float kPI = 3.14159265358979323846f;

__device__ __forceinline__ half2v pack_w1(float w) {
    return __builtin_bit_cast(half2v, __builtin_amdgcn_cvt_pkrtz(1.0f, w));
}

// ---------------------------------------------------------------------------
// Stage 1: ramp filter (R16 verbatim): truncated symmetric convolution,
// (f, DELTA) fp16 packing. word (a*512+d)*2+bc = fp16x2 (xf[d], xf[d+1]-xf[d]).
// Grid: 90 blocks = (bc, 4 angles) x 512 threads; float4 input loads.
// ---------------------------------------------------------------------------
__global__ __launch_bounds__(512) void ramp_filter_kernel(
    const float* __restrict__ x, unsigned* __restrict__ xfh) {
    __shared__ float rp[4][640];
    __shared__ float xf[4][D_DET + 1];

    const int blk = blockIdx.x;
    const int bc  = blk / 45;            // 0..1
    const int a0  = (blk % 45) * 4;
    const int d   = threadIdx.x;

    float4 q = *(const float4*)(x + (bc * D_DET + d) * N_ANG + a0);
    rp[0][64 + d] = q.x;
    rp[1][64 + d] = q.y;
    rp[2][64 + d] = q.z;
    rp[3][64 + d] = q.w;
    if (d < 64) {
        #pragma unroll
        for (int r = 0; r < 4; ++r) { rp[r][d] = 0.0f; rp[r][576 + d] = 0.0f; }
    }
    if (d < 4) xf[d][D_DET] = 0.0f;
    __syncthreads();

    constexpr float PI_ = 3.14159265358979323846f;
    #pragma unroll
    for (int r = 0; r < 4; ++r) {
        const float* rm = &rp[r][64 + d];
        float acc = 0.5f * rm[0];
        #pragma unroll
        for (int k = 0; k < (T_MAX + 1) / 2; ++k) {
            const int   t = 2 * k + 1;
            const float h = -2.0f / (PI_ * PI_ * (float)(t * t));
            acc = fmaf(rm[-t] + rm[t], h, acc);
        }
        xf[r][d] = acc;
    }
    __syncthreads();

    #pragma unroll
    for (int r = 0; r < 4; ++r) {
        const float f0 = xf[r][d];
        const float dl = xf[r][d + 1] - f0;
        const unsigned lo = __half_as_ushort(__float2half_rn(f0));
        const unsigned hi = __half_as_ushort(__float2half_rn(dl));
        xfh[((a0 + r) * D_DET + d) * 2 + bc] = (hi << 16) | lo;
    }
}

// ---------------------------------------------------------------------------
// Stage 2: backprojection, dual-pipe split + kernarg trig (scalar pipe).
// trig rides in a by-value kernarg struct: loop-uniform tt.cs[a] lowers to
// s_load (scalar cache) -- zero LDS-pipe and zero vL1D cost, and unlike
// R20's rotation recurrence every angle's address is INDEPENDENT (full
// memory-level parallelism, compiler can keep 4-6 gathers in flight).
//   half 0: angles 0..71   -> global 8B gathers (vL1D pipe)
//   half 1: angles 72..179 -> staged 32-cell windows (LDS pipe), per-angle
//           bias batch-read as float4 every 4 angles.
// Per-CU ledger: vL1D 4*(288*16+432)=20.2k cyc = 8.4us | LDS 17.3k = 7.2us
// | VALU ~6-7us | scalar: trig. Block = 512 thr over 16x16 tile, 4 blk/CU.
// ---------------------------------------------------------------------------
__global__ __launch_bounds__(512) void backproj_kernel(
    const uint2* __restrict__ xfh, float* __restrict__ out, TrigTab tt) {
    __shared__ float  dminF[AL];         // bias = 255.5 - dmin (16B aligned)
    __shared__ int    dminI[AL];
    __shared__ uint2  win[AL * WIN];     // 27.6 KB window buffer
    __shared__ float2 red[256];

    const int tid = threadIdx.x;
    const int bi  = blockIdx.x >> 5;     // 32 i-tiles of 16
    const int bj  = blockIdx.x & 31;     // 32 j-tiles of 16
    const int i0  = bi << 4;
    const int j0  = bj << 4;

    // Prologue: per-angle window start for LDS-half angles.
    if (tid < AL) {
        float2 cs = tt.cs[AG + tid];
        float c5 = cs.x, s5 = cs.y;
        float x0 = (float)j0 * (2.0f / 511.0f) - 1.0f;
        float x1 = (float)(j0 + 15) * (2.0f / 511.0f) - 1.0f;
        float y0 = (float)i0 * (2.0f / 511.0f) - 1.0f;
        float y1 = (float)(i0 + 15) * (2.0f / 511.0f) - 1.0f;
        float pmin = 255.5f + fminf(c5 * x0, c5 * x1)
                            + fminf(-s5 * y0, -s5 * y1);
        int dmin = (int)floorf(pmin) - 1;
        dmin = dmin < 0 ? 0 : (dmin > (D_DET - WIN) ? (D_DET - WIN) : dmin);
        dmin &= ~1;                      // 16B-aligned staging source
        dminI[tid] = dmin;
        dminF[tid] = 255.5f - (float)dmin;
    }
    __syncthreads();

    // Stage windows: AL angles x 16 uint4, coalesced from L2.
    {
        const uint4* __restrict__ src4 = (const uint4*)xfh;
        uint4* win4 = (uint4*)win;
        for (int f = tid; f < AL * (WIN / 2); f += 512) {
            int a    = f >> 4;           // local angle; 16 uint4 per angle
            int e    = f & 15;
            int dmin = dminI[a];
            win4[f]  = src4[((((AG + a) << 9) + dmin) >> 1) + e];
        }
    }
    __syncthreads();

    const int half = tid >> 8;
    const int sub  = (tid >> 6) & 3;
    const int lane = tid & 63;
    const int px   = tid & 255;
    const int i = i0 + ((sub >> 1) << 3) + (lane >> 3);
    const int j = j0 + ((sub & 1) << 3) + (lane & 7);

    const float xP = (float)j * (2.0f / 511.0f) - 1.0f;
    const float yP = (float)i * (2.0f / 511.0f) - 1.0f;
    const float m  = xP * xP + yP * yP;
    const bool inc = (m <= 1.0f);
    const float xS = inc ? xP : 0.0f;    // sanitize: out-circle -> pc=255.5
    const float yS = inc ? yP : 0.0f;

    float a0 = 0.0f, a1 = 0.0f;
    if (__any(inc)) {
        if (half == 0) {
            // vL1D pipe: global gathers; trig via s_load (scalar pipe).
            #pragma unroll 6
            for (int a = 0; a < AG; ++a) {
                float2 t  = tt.cs[a];
                float pc  = fmaf(xS, t.x, fmaf(yS, -t.y, 255.5f));
                pc        = fmaxf(pc, 0.0f);
                int   fi  = (int)pc;
                float w   = __builtin_amdgcn_fractf(pc);
                half2v hw = pack_w1(w);
                uint2  g  = xfh[(a << 9) + fi];
                a0 = __builtin_amdgcn_fdot2(hw, __builtin_bit_cast(half2v, g.x), a0, false);
                a1 = __builtin_amdgcn_fdot2(hw, __builtin_bit_cast(half2v, g.y), a1, false);
            }
        } else {
            // LDS pipe: window reads; bias batch-read (b128) every 4 angles.
            const float4* __restrict__ bias4 = (const float4*)dminF;
            #pragma unroll 3
            for (int gq = 0; gq < AL / 4; ++gq) {
                const float4 bs = bias4[gq];
                #pragma unroll
                for (int jj = 0; jj < 4; ++jj) {
                    const int al = gq * 4 + jj;
                    const float bias = (jj == 0) ? bs.x : (jj == 1) ? bs.y
                                     : (jj == 2) ? bs.z : bs.w;
                    float2 t  = tt.cs[AG + al];
                    float pcW = fmaf(xS, t.x, fmaf(yS, -t.y, bias));
                    pcW       = fminf(fmaxf(pcW, 0.0f), (float)(WIN - 1));
                    int   fi  = (int)pcW;
                    float w   = __builtin_amdgcn_fractf(pcW);
                    half2v hw = pack_w1(w);
                    uint2  g  = win[(al << 5) + fi];
                    a0 = __builtin_amdgcn_fdot2(hw, __builtin_bit_cast(half2v, g.x), a0, false);
                    a1 = __builtin_amdgcn_fdot2(hw, __builtin_bit_cast(half2v, g.y), a1, false);
                }
            }
        }
    }

    if (half == 1) red[px] = make_float2(a0, a1);
    __syncthreads();
    if (half == 0) {
        const float2 r = red[px];
        const float msk = inc ? (kPI / (2.0f * (float)N_ANG)) : 0.0f;
        const int p = i * S_IMG + j;
        out[p]        = (a0 + r.x) * msk;
        out[NPIX + p] = (a1 + r.y) * msk;
    }
}

// ---------------------------------------------------------------------------
extern "C" void kernel_launch(void* const* d_in, const int* in_sizes, int n_in,
                              void* d_out, int out_size, void* d_ws, size_t ws_size,
                              hipStream_t stream) {
    const float* x   = (const float*)d_in[0];
    float*       out = (float*)d_out;
    unsigned*    xfh = (unsigned*)d_ws;  // 737,280 B

    TrigTab tt;
    for (int a = 0; a < N_ANG; ++a) {    // host double-precision trig
        double th = (double)a * 3.14159265358979323846 / 180.0;
        tt.cs[a].x = (float)(cos(th) * 255.5);
        tt.cs[a].y = (float)(sin(th) * 255.5);
    }

    ramp_filter_kernel<<<90, 512, 0, stream>>>(x, xfh);
    backproj_kernel<<<1024, 512, 0, stream>>>((const uint2*)xfh, out, tt);
}